// Round 1
// baseline (11444.101 us; speedup 1.0000x reference)
//
#include <hip/hip_runtime.h>
#include <hip/hip_bf16.h>
#include <hip/hip_fp16.h>

// LSTM_RNN: B=128, T=512, E=256, U=512 (4U=2048 gate cols), VOCAB=32000.
// Strategy: persistent-weight recurrent kernel.
//   - 64 workgroups, each owns 8 hidden units (32 gate columns: [i|f] tile, [g|o] tile).
//   - Weight slice [768 x 32] ([Wx;Wh] columns) in LDS as fp16 for ALL 512 steps.
//   - Per step: z-slab = [128,768]@[768,32] via v_mfma_f32_16x16x16f16 (legacy builtin,
//     V4h operands -- type-stable), A-frags streamed from global (X precomputed fp16,
//     H double-buffered fp16), gates/c/h in registers via shfl_xor(8).
//   - Inter-wg step barrier: per-wg flag cacheline, release store + 64-lane poll.
// ws layout (needs ~32.3 MiB):
//   X   fp16 [T][B][E]  @ 0          (33,554,432 B)
//   H0  fp16 [B][U]     @ 33,554,432 (131,072 B)
//   H1  fp16 [B][U]     @ 33,685,504 (131,072 B)
//   flags int[64*16]    @ 33,816,576 (4,096 B)

#define B_ 128
#define T_ 512
#define E_ 256
#define U_ 512
#define NG_ 64      // workgroups (unit groups)
#define US_ 8       // units per wg
#define NCOL_ 32    // 4 gates * US_
#define KTOT_ 768   // E + U
#define KP_ 776     // padded K: stride 388 dwords -> 2-way LDS aliasing (free, m136)

typedef __attribute__((ext_vector_type(4))) _Float16 half4;
typedef __attribute__((ext_vector_type(4))) float floatx4;

__device__ __forceinline__ float sigmf(float x) { return 1.0f / (1.0f + __expf(-x)); }
__device__ __forceinline__ float tanh_f(float x) { return 2.0f / (1.0f + __expf(-2.0f * x)) - 1.0f; }

__global__ void init_ws_kernel(unsigned int* __restrict__ h0w,
                               unsigned int* __restrict__ flagw) {
  int gid = blockIdx.x * blockDim.x + threadIdx.x;
  int n = blockDim.x * gridDim.x;
  for (int i = gid; i < (B_ * U_ / 2); i += n) h0w[i] = 0u;  // H0 = zeros (fp16)
  for (int i = gid; i < 1024; i += n) flagw[i] = 0u;         // flags = 0
}

// X[t][b][e] = (fp16) emb[sentence[b][t]][e]; one thread = 8 elements.
__global__ void prep_x_kernel(const int* __restrict__ sent,
                              const float* __restrict__ emb,
                              _Float16* __restrict__ X) {
  int gid = blockIdx.x * blockDim.x + threadIdx.x;  // 2,097,152 total
  int e8 = gid & 31;          // 32 chunks of 8 = 256 = E
  int row = gid >> 5;         // row = t*128 + b
  int b = row & 127;
  int t = row >> 7;
  int word = sent[b * T_ + t];
  const float* src = emb + (size_t)word * E_ + e8 * 8;
  float4 v0 = *(const float4*)(src);
  float4 v1 = *(const float4*)(src + 4);
  half4 o0 = {(_Float16)v0.x, (_Float16)v0.y, (_Float16)v0.z, (_Float16)v0.w};
  half4 o1 = {(_Float16)v1.x, (_Float16)v1.y, (_Float16)v1.z, (_Float16)v1.w};
  _Float16* dst = X + (size_t)row * E_ + e8 * 8;
  *(half4*)dst = o0;
  *(half4*)(dst + 4) = o1;
}

__global__ __launch_bounds__(256, 1) void lstm_kernel(
    const _Float16* __restrict__ X,
    const float* __restrict__ Wx, const float* __restrict__ Wh,
    const float* __restrict__ bias,
    _Float16* __restrict__ H0, _Float16* __restrict__ H1,
    int* flags) {
  // Wl[c][k] fp16, c in [0,32): c>>3 = gate (i,f,g,o), c&7 = unit offset.
  __shared__ __align__(16) _Float16 Wl[NCOL_ * KP_];  // 49,664 B

  const int g = blockIdx.x;
  const int tid = threadIdx.x;
  const int lane = tid & 63;
  const int wave = tid >> 6;   // 4 waves
  const int p16 = lane & 15;
  const int quad = lane >> 4;

  // ---- one-time: stage weight slice into LDS (consecutive tid -> consecutive c) ----
  for (int idx = tid; idx < NCOL_ * KTOT_; idx += 256) {
    int c = idx & (NCOL_ - 1);
    int k = idx >> 5;
    int C = (c >> 3) * 512 + g * US_ + (c & 7);  // global gate column
    float w = (k < E_) ? Wx[(size_t)k * 2048 + C] : Wh[(size_t)(k - E_) * 2048 + C];
    Wl[c * KP_ + k] = (_Float16)w;
  }
  __syncthreads();

  // epilogue constants: lanes 0-7 of each 16 hold (i,g), lanes 8-15 hold (f,o)
  const bool lo = (p16 < 8);
  const int uo = p16 & 7;
  const int gu = g * US_ + uo;                       // global unit id
  const float bias0 = bias[(lo ? 0 : 512) + gu];     // i or f
  const float bias1 = bias[(lo ? 1024 : 1536) + gu]; // g or o

  float cst[8];  // c-state: [mt*4+r], valid on lo lanes
#pragma unroll
  for (int i = 0; i < 8; ++i) cst[i] = 0.0f;

  // A-fragment row/k bases (16x16x16 f16: A[m=lane&15][k=quad*4+j])
  const int m0 = (wave * 2 + 0) * 16 + p16;
  const int m1 = (wave * 2 + 1) * 16 + p16;
  const int ko = quad * 4;

  for (int t = 0; t < T_; ++t) {
    // ---- wait: all wgs have published h_t ----
    if (wave == 0) {
      for (;;) {
        int v = __hip_atomic_load(&flags[lane * 16], __ATOMIC_RELAXED,
                                  __HIP_MEMORY_SCOPE_AGENT);
        if (__all(v >= t)) break;
        __builtin_amdgcn_s_sleep(2);
      }
      __threadfence();  // acquire: invalidate stale L1/L2 h lines
    }
    __syncthreads();

    const _Float16* __restrict__ Hin = (t & 1) ? H1 : H0;
    _Float16* __restrict__ Hout = (t & 1) ? H0 : H1;

    floatx4 acc[2][2];
#pragma unroll
    for (int i = 0; i < 2; ++i)
#pragma unroll
      for (int j = 0; j < 2; ++j) acc[i][j] = (floatx4){0.f, 0.f, 0.f, 0.f};

    const _Float16* xr0 = X + ((size_t)t * B_ + m0) * E_ + ko;
    const _Float16* xr1 = X + ((size_t)t * B_ + m1) * E_ + ko;
    const _Float16* hr0 = Hin + (size_t)m0 * U_ + ko;
    const _Float16* hr1 = Hin + (size_t)m1 * U_ + ko;

    // ---- K loop, x part: k = kk*16 in [0,256) ----
#pragma unroll
    for (int kk = 0; kk < 16; ++kk) {
      half4 a0 = *(const half4*)(xr0 + kk * 16);
      half4 a1 = *(const half4*)(xr1 + kk * 16);
      half4 b0 = *(const half4*)(&Wl[(0 * 16 + p16) * KP_ + kk * 16 + ko]);
      half4 b1 = *(const half4*)(&Wl[(1 * 16 + p16) * KP_ + kk * 16 + ko]);
      acc[0][0] = __builtin_amdgcn_mfma_f32_16x16x16f16(a0, b0, acc[0][0], 0, 0, 0);
      acc[0][1] = __builtin_amdgcn_mfma_f32_16x16x16f16(a0, b1, acc[0][1], 0, 0, 0);
      acc[1][0] = __builtin_amdgcn_mfma_f32_16x16x16f16(a1, b0, acc[1][0], 0, 0, 0);
      acc[1][1] = __builtin_amdgcn_mfma_f32_16x16x16f16(a1, b1, acc[1][1], 0, 0, 0);
    }
    // ---- K loop, h part: k = 256 + kk*16 ----
#pragma unroll
    for (int kk = 0; kk < 32; ++kk) {
      half4 a0 = *(const half4*)(hr0 + kk * 16);
      half4 a1 = *(const half4*)(hr1 + kk * 16);
      half4 b0 = *(const half4*)(&Wl[(0 * 16 + p16) * KP_ + 256 + kk * 16 + ko]);
      half4 b1 = *(const half4*)(&Wl[(1 * 16 + p16) * KP_ + 256 + kk * 16 + ko]);
      acc[0][0] = __builtin_amdgcn_mfma_f32_16x16x16f16(a0, b0, acc[0][0], 0, 0, 0);
      acc[0][1] = __builtin_amdgcn_mfma_f32_16x16x16f16(a0, b1, acc[0][1], 0, 0, 0);
      acc[1][0] = __builtin_amdgcn_mfma_f32_16x16x16f16(a1, b0, acc[1][0], 0, 0, 0);
      acc[1][1] = __builtin_amdgcn_mfma_f32_16x16x16f16(a1, b1, acc[1][1], 0, 0, 0);
    }

    // ---- gates + state update. C/D: col=lane&15, row=quad*4+r (m89-verified). ----
#pragma unroll
    for (int mt = 0; mt < 2; ++mt) {
#pragma unroll
      for (int r = 0; r < 4; ++r) {
        float z0 = acc[mt][0][r] + bias0;  // i (lo) / f (hi)
        float z1 = acc[mt][1][r] + bias1;  // g (lo) / o (hi)
        float s0 = sigmf(z0);
        float s1 = lo ? tanh_f(z1) : sigmf(z1);
        float prod = s0 * s1;                              // i*g on lo lanes
        float fg = __shfl_xor(lo ? prod : s0, 8, 64);      // lo receives f
        float og = __shfl_xor(s1, 8, 64);                  // lo receives o
        if (lo) {
          float cn = fg * cst[mt * 4 + r] + prod;
          cst[mt * 4 + r] = cn;
          float h = og * tanh_f(cn);
          int row = (wave * 2 + mt) * 16 + quad * 4 + r;
          Hout[(size_t)row * U_ + gu] = (_Float16)h;
        }
      }
    }

    // ---- publish h_{t+1} ----
    __threadfence();   // drain our stores to device scope
    __syncthreads();
    if (tid == 0)
      __hip_atomic_store(&flags[g * 16], t + 1, __ATOMIC_RELEASE,
                         __HIP_MEMORY_SCOPE_AGENT);
  }
}

// MLP head: one block per batch row. h(512)->relu 128->relu 64->sigmoid 1.
__global__ void head_kernel(const _Float16* __restrict__ H0,
                            const float* __restrict__ W1, const float* __restrict__ b1,
                            const float* __restrict__ W2, const float* __restrict__ b2,
                            const float* __restrict__ W3, const float* __restrict__ b3,
                            float* __restrict__ out) {
  __shared__ float hs[512];
  __shared__ float h1[128];
  __shared__ float h2[64];
  int row = blockIdx.x;
  int tid = threadIdx.x;  // 128 threads
  for (int k = tid; k < 512; k += 128) hs[k] = (float)H0[(size_t)row * U_ + k];
  __syncthreads();
  float a = b1[tid];
  for (int k = 0; k < 512; ++k) a += hs[k] * W1[k * 128 + tid];
  h1[tid] = fmaxf(a, 0.0f);
  __syncthreads();
  if (tid < 64) {
    float a2 = b2[tid];
    for (int k = 0; k < 128; ++k) a2 += h1[k] * W2[k * 64 + tid];
    h2[tid] = fmaxf(a2, 0.0f);
  }
  __syncthreads();
  if (tid == 0) {
    float a3 = b3[0];
    for (int k = 0; k < 64; ++k) a3 += h2[k] * W3[k];
    out[row] = 1.0f / (1.0f + __expf(-a3));
  }
}

extern "C" void kernel_launch(void* const* d_in, const int* in_sizes, int n_in,
                              void* d_out, int out_size, void* d_ws, size_t ws_size,
                              hipStream_t stream) {
  const int* sent = (const int*)d_in[0];
  const float* emb = (const float*)d_in[1];
  const float* Wx = (const float*)d_in[2];
  const float* Wh = (const float*)d_in[3];
  const float* b = (const float*)d_in[4];
  const float* W1 = (const float*)d_in[5];
  const float* b1 = (const float*)d_in[6];
  const float* W2 = (const float*)d_in[7];
  const float* b2 = (const float*)d_in[8];
  const float* W3 = (const float*)d_in[9];
  const float* b3 = (const float*)d_in[10];
  float* out = (float*)d_out;

  char* ws = (char*)d_ws;
  _Float16* X = (_Float16*)(ws);
  _Float16* H0 = (_Float16*)(ws + (size_t)33554432);
  _Float16* H1 = (_Float16*)(ws + (size_t)33554432 + 131072);
  int* flags = (int*)(ws + (size_t)33554432 + 262144);

  init_ws_kernel<<<64, 256, 0, stream>>>((unsigned int*)H0, (unsigned int*)flags);
  prep_x_kernel<<<8192, 256, 0, stream>>>(sent, emb, X);
  lstm_kernel<<<NG_, 256, 0, stream>>>(X, Wx, Wh, b, H0, H1, flags);
  head_kernel<<<128, 128, 0, stream>>>(H0, W1, b1, W2, b2, W3, b3, out);
}

// Round 2
// 7003.441 us; speedup vs baseline: 1.6341x; 1.6341x over previous
//
#include <hip/hip_runtime.h>
#include <hip/hip_bf16.h>
#include <hip/hip_fp16.h>

// LSTM_RNN: B=128, T=512, E=256, U=512 (4U=2048 gate cols), VOCAB=32000.
// R2: persistent-weight recurrent kernel, NO cache-maintenance fences.
//   - Cross-XCD data (H, flags) uses relaxed AGENT-scope atomics -> sc0/sc1
//     per-access coherent (LLC), never buffer_wbl2/buffer_inv (R1's 20us/step).
//   - Ordering: __syncthreads() drains vmcnt(0) before s_barrier, so H stores
//     are LLC-visible before the flag store; consumer loads issue only after
//     the poll branch resolves (in-order issue). No __threadfence anywhere.
//   - 512 thr/wg (8 waves, 2/SIMD) for MFMA+mem latency hiding; 1 M-tile/wave.
//   - H row prefetched into 32 ulongs BEFORE x-part MFMAs (overlap LLC latency).
//   - KP=772 halves (386-dword row stride): ds_read_b64 phase covers all 32
//     banks once -> conflict-free (R1 KP=776 was 4-way).
// ws layout (~32.3 MiB):
//   X   fp16 [T][B][E]  @ 0          (33,554,432 B)
//   H0  fp16 [B][U]     @ 33,554,432 (131,072 B)
//   H1  fp16 [B][U]     @ 33,685,504 (131,072 B)
//   flags int[64*32]    @ 33,816,576 (8,192 B)

#define B_ 128
#define T_ 512
#define E_ 256
#define U_ 512
#define NG_ 64      // workgroups (unit groups)
#define US_ 8       // units per wg
#define NCOL_ 32    // 4 gates * US_
#define KTOT_ 768   // E + U
#define KP_ 772     // padded K (halves): 386-dword stride, conflict-free b64

typedef __attribute__((ext_vector_type(4))) _Float16 half4;
typedef __attribute__((ext_vector_type(4))) float floatx4;

__device__ __forceinline__ float sigmf(float x) { return 1.0f / (1.0f + __expf(-x)); }
__device__ __forceinline__ float tanh_f(float x) { return 2.0f / (1.0f + __expf(-2.0f * x)) - 1.0f; }

__global__ void init_ws_kernel(unsigned int* __restrict__ h0w,
                               unsigned int* __restrict__ flagw) {
  int gid = blockIdx.x * blockDim.x + threadIdx.x;
  int n = blockDim.x * gridDim.x;
  for (int i = gid; i < (B_ * U_ / 2); i += n) h0w[i] = 0u;  // H0 = zeros (fp16)
  for (int i = gid; i < 2048; i += n) flagw[i] = 0u;         // flags = 0
}

// X[t][b][e] = (fp16) emb[sentence[b][t]][e]; one thread = 8 elements.
__global__ void prep_x_kernel(const int* __restrict__ sent,
                              const float* __restrict__ emb,
                              _Float16* __restrict__ X) {
  int gid = blockIdx.x * blockDim.x + threadIdx.x;  // 2,097,152 total
  int e8 = gid & 31;          // 32 chunks of 8 = 256 = E
  int row = gid >> 5;         // row = t*128 + b
  int b = row & 127;
  int t = row >> 7;
  int word = sent[b * T_ + t];
  const float* src = emb + (size_t)word * E_ + e8 * 8;
  float4 v0 = *(const float4*)(src);
  float4 v1 = *(const float4*)(src + 4);
  half4 o0 = {(_Float16)v0.x, (_Float16)v0.y, (_Float16)v0.z, (_Float16)v0.w};
  half4 o1 = {(_Float16)v1.x, (_Float16)v1.y, (_Float16)v1.z, (_Float16)v1.w};
  _Float16* dst = X + (size_t)row * E_ + e8 * 8;
  *(half4*)dst = o0;
  *(half4*)(dst + 4) = o1;
}

__global__ __launch_bounds__(512, 1) void lstm_kernel(
    const _Float16* __restrict__ X,
    const float* __restrict__ Wx, const float* __restrict__ Wh,
    const float* __restrict__ bias,
    _Float16* __restrict__ H0, _Float16* __restrict__ H1,
    int* flags) {
  // Wl[c][k] fp16, c in [0,32): c>>3 = gate (i,f,g,o), c&7 = unit offset.
  __shared__ __align__(16) _Float16 Wl[NCOL_ * KP_];  // 49,408 B

  const int g = blockIdx.x;
  const int tid = threadIdx.x;
  const int lane = tid & 63;
  const int wave = tid >> 6;   // 8 waves; wave = M-tile (rows wave*16..wave*16+15)
  const int p16 = lane & 15;
  const int quad = lane >> 4;

  // ---- one-time: stage weight slice into LDS ----
  for (int idx = tid; idx < NCOL_ * KTOT_; idx += 512) {
    int c = idx & (NCOL_ - 1);
    int k = idx >> 5;
    int C = (c >> 3) * 512 + g * US_ + (c & 7);  // global gate column
    float w = (k < E_) ? Wx[(size_t)k * 2048 + C] : Wh[(size_t)(k - E_) * 2048 + C];
    Wl[c * KP_ + k] = (_Float16)w;
  }
  __syncthreads();

  // epilogue constants: lanes 0-7 of each 16 hold (i,g), lanes 8-15 hold (f,o)
  const bool lo = (p16 < 8);
  const int uo = p16 & 7;
  const int gu = g * US_ + uo;                       // global unit id
  const float bias0 = bias[(lo ? 0 : 512) + gu];     // i or f
  const float bias1 = bias[(lo ? 1024 : 1536) + gu]; // g or o

  float cst[4];  // c-state per row r (rows quad*4+r of this wave's M-tile)
#pragma unroll
  for (int i = 0; i < 4; ++i) cst[i] = 0.0f;

  // A-fragment (16x16x16 f16): A[m=lane&15][k=quad*4+j]
  const int m = wave * 16 + p16;   // global batch row this lane loads
  const int ko = quad * 4;

  const _Float16* bp0 = &Wl[(0 * 16 + p16) * KP_ + ko];  // [i|f] tile B-col
  const _Float16* bp1 = &Wl[(1 * 16 + p16) * KP_ + ko];  // [g|o] tile B-col

  for (int t = 0; t < T_; ++t) {
    // ---- wait: all wgs have published h_t (relaxed agent loads, no fences) ----
    if (wave == 0) {
      for (;;) {
        int v = __hip_atomic_load(&flags[lane * 32], __ATOMIC_RELAXED,
                                  __HIP_MEMORY_SCOPE_AGENT);
        if (__all(v >= t)) break;
        __builtin_amdgcn_s_sleep(1);
      }
    }
    __syncthreads();  // compiler+HW ordering: loads below can't move above this

    const _Float16* __restrict__ Hin = (t & 1) ? H1 : H0;
    _Float16* __restrict__ Hout = (t & 1) ? H0 : H1;

    // ---- prefetch this lane's H row slice (32 x 8B, coherent LLC loads) ----
    const unsigned long long* hrow =
        (const unsigned long long*)(Hin + (size_t)m * U_);
    unsigned long long hbuf[32];
#pragma unroll
    for (int kk = 0; kk < 32; ++kk)
      hbuf[kk] = __hip_atomic_load(hrow + kk * 4 + quad, __ATOMIC_RELAXED,
                                   __HIP_MEMORY_SCOPE_AGENT);

    floatx4 acc[2];
    acc[0] = (floatx4){0.f, 0.f, 0.f, 0.f};
    acc[1] = (floatx4){0.f, 0.f, 0.f, 0.f};

    // ---- x part: k in [0,256); plain cached loads (X is read-only) ----
    const _Float16* xr = X + ((size_t)t * B_ + m) * E_ + ko;
#pragma unroll
    for (int kk = 0; kk < 16; ++kk) {
      half4 a = *(const half4*)(xr + kk * 16);
      half4 b0 = *(const half4*)(bp0 + kk * 16);
      half4 b1 = *(const half4*)(bp1 + kk * 16);
      acc[0] = __builtin_amdgcn_mfma_f32_16x16x16f16(a, b0, acc[0], 0, 0, 0);
      acc[1] = __builtin_amdgcn_mfma_f32_16x16x16f16(a, b1, acc[1], 0, 0, 0);
    }
    // ---- h part: k in [256,768); A-frags from prefetched hbuf ----
#pragma unroll
    for (int kk = 0; kk < 32; ++kk) {
      half4 a = __builtin_bit_cast(half4, hbuf[kk]);
      half4 b0 = *(const half4*)(bp0 + 256 + kk * 16);
      half4 b1 = *(const half4*)(bp1 + 256 + kk * 16);
      acc[0] = __builtin_amdgcn_mfma_f32_16x16x16f16(a, b0, acc[0], 0, 0, 0);
      acc[1] = __builtin_amdgcn_mfma_f32_16x16x16f16(a, b1, acc[1], 0, 0, 0);
    }

    // ---- gates + state update. C/D: col=lane&15, row=quad*4+r. ----
#pragma unroll
    for (int r = 0; r < 4; ++r) {
      float z0 = acc[0][r] + bias0;  // i (lo) / f (hi)
      float z1 = acc[1][r] + bias1;  // g (lo) / o (hi)
      float s0 = sigmf(z0);
      float s1 = lo ? tanh_f(z1) : sigmf(z1);
      float prod = s0 * s1;                              // i*g on lo lanes
      float fg = __shfl_xor(lo ? prod : s0, 8, 64);      // lo receives f
      float og = __shfl_xor(s1, 8, 64);                  // lo receives o
      if (lo) {
        float cn = fg * cst[r] + prod;
        cst[r] = cn;
        float h = og * tanh_f(cn);
        int row = wave * 16 + quad * 4 + r;
        _Float16 hf = (_Float16)h;
        unsigned short hb = __builtin_bit_cast(unsigned short, hf);
        __hip_atomic_store((unsigned short*)&Hout[(size_t)row * U_ + gu], hb,
                           __ATOMIC_RELAXED, __HIP_MEMORY_SCOPE_AGENT);
      }
    }

    // ---- publish h_{t+1}: syncthreads drains vmcnt(0) for ALL waves first ----
    __syncthreads();
    if (tid == 0)
      __hip_atomic_store(&flags[g * 32], t + 1, __ATOMIC_RELAXED,
                         __HIP_MEMORY_SCOPE_AGENT);
  }
}

// MLP head: one block per batch row. h(512)->relu 128->relu 64->sigmoid 1.
__global__ void head_kernel(const _Float16* __restrict__ H0,
                            const float* __restrict__ W1, const float* __restrict__ b1,
                            const float* __restrict__ W2, const float* __restrict__ b2,
                            const float* __restrict__ W3, const float* __restrict__ b3,
                            float* __restrict__ out) {
  __shared__ float hs[512];
  __shared__ float h1[128];
  __shared__ float h2[64];
  int row = blockIdx.x;
  int tid = threadIdx.x;  // 128 threads
  for (int k = tid; k < 512; k += 128) hs[k] = (float)H0[(size_t)row * U_ + k];
  __syncthreads();
  float a = b1[tid];
  for (int k = 0; k < 512; ++k) a += hs[k] * W1[k * 128 + tid];
  h1[tid] = fmaxf(a, 0.0f);
  __syncthreads();
  if (tid < 64) {
    float a2 = b2[tid];
    for (int k = 0; k < 128; ++k) a2 += h1[k] * W2[k * 64 + tid];
    h2[tid] = fmaxf(a2, 0.0f);
  }
  __syncthreads();
  if (tid == 0) {
    float a3 = b3[0];
    for (int k = 0; k < 64; ++k) a3 += h2[k] * W3[k];
    out[row] = 1.0f / (1.0f + __expf(-a3));
  }
}

extern "C" void kernel_launch(void* const* d_in, const int* in_sizes, int n_in,
                              void* d_out, int out_size, void* d_ws, size_t ws_size,
                              hipStream_t stream) {
  const int* sent = (const int*)d_in[0];
  const float* emb = (const float*)d_in[1];
  const float* Wx = (const float*)d_in[2];
  const float* Wh = (const float*)d_in[3];
  const float* b = (const float*)d_in[4];
  const float* W1 = (const float*)d_in[5];
  const float* b1 = (const float*)d_in[6];
  const float* W2 = (const float*)d_in[7];
  const float* b2 = (const float*)d_in[8];
  const float* W3 = (const float*)d_in[9];
  const float* b3 = (const float*)d_in[10];
  float* out = (float*)d_out;

  char* ws = (char*)d_ws;
  _Float16* X = (_Float16*)(ws);
  _Float16* H0 = (_Float16*)(ws + (size_t)33554432);
  _Float16* H1 = (_Float16*)(ws + (size_t)33554432 + 131072);
  int* flags = (int*)(ws + (size_t)33554432 + 262144);

  init_ws_kernel<<<64, 256, 0, stream>>>((unsigned int*)H0, (unsigned int*)flags);
  prep_x_kernel<<<8192, 256, 0, stream>>>(sent, emb, X);
  lstm_kernel<<<NG_, 512, 0, stream>>>(X, Wx, Wh, b, H0, H1, flags);
  head_kernel<<<128, 128, 0, stream>>>(H0, W1, b1, W2, b2, W3, b3, out);
}

// Round 3
// 2845.515 us; speedup vs baseline: 4.0218x; 2.4612x over previous
//
#include <hip/hip_runtime.h>
#include <hip/hip_bf16.h>
#include <hip/hip_fp16.h>

// LSTM_RNN: B=128, T=512, E=256, U=512. R3: quartered batch + fat slices.
//   - 128 wgs = 4 batch-quarters (32 rows) x 32 unit-slices (16 units, 64 gate
//     cols). Quarters are fully independent sync domains (poll 32 flags only).
//   - Weights [768 x 64] fp16 in LDS (98.8 KB, KP=772). H quarter-slab staged
//     per step via lane-contiguous 8B agent-scope loads (coalesced 64B lines,
//     ~16x fewer LLC transactions than R2) -> padded LDS slab -> ds_read frags.
//   - 8 waves: K-split (kh0: x + h[256:512), kh1: h[0:256)), LDS acc reduce.
//     x-part MFMAs run BEFORE the flag poll (no h_t dependency) - off the
//     critical path.
//   - LDS total 140,288 B static (gfx950: 160 KiB addressable). 1 wg/CU.
// ws layout (~33.8 MiB):
//   X   fp16 [T][B][E]  @ 0          (33,554,432 B)
//   H0  fp16 [B][U]     @ 33,554,432 (131,072 B)
//   H1  fp16 [B][U]     @ 33,685,504 (131,072 B)
//   flags int[128*16]   @ 33,816,576 (8,192 B)

#define B_ 128
#define T_ 512
#define E_ 256
#define U_ 512
#define NWG_ 128
#define KP_ 772     // padded weight K (halves): 386-dword stride, ~conflict-free
#define HROW_ 520   // halves per H-slab row (512 + 8 pad): 260-dword stride

typedef __attribute__((ext_vector_type(4))) _Float16 half4;
typedef __attribute__((ext_vector_type(4))) float floatx4;
typedef unsigned long long u64t;

__device__ __forceinline__ float sigmf(float x) { return 1.0f / (1.0f + __expf(-x)); }
__device__ __forceinline__ float tanh_f(float x) { return 2.0f / (1.0f + __expf(-2.0f * x)) - 1.0f; }

__global__ void init_ws_kernel(unsigned int* __restrict__ h0w,
                               unsigned int* __restrict__ flagw) {
  int gid = blockIdx.x * blockDim.x + threadIdx.x;
  int n = blockDim.x * gridDim.x;
  for (int i = gid; i < (B_ * U_ / 2); i += n) h0w[i] = 0u;  // H0 = zeros (fp16)
  for (int i = gid; i < 2048; i += n) flagw[i] = 0u;         // flags = 0
}

// X[t][b][e] = (fp16) emb[sentence[b][t]][e]; one thread = 8 elements.
__global__ void prep_x_kernel(const int* __restrict__ sent,
                              const float* __restrict__ emb,
                              _Float16* __restrict__ X) {
  int gid = blockIdx.x * blockDim.x + threadIdx.x;  // 2,097,152 total
  int e8 = gid & 31;
  int row = gid >> 5;         // row = t*128 + b
  int b = row & 127;
  int t = row >> 7;
  int word = sent[b * T_ + t];
  const float* src = emb + (size_t)word * E_ + e8 * 8;
  float4 v0 = *(const float4*)(src);
  float4 v1 = *(const float4*)(src + 4);
  half4 o0 = {(_Float16)v0.x, (_Float16)v0.y, (_Float16)v0.z, (_Float16)v0.w};
  half4 o1 = {(_Float16)v1.x, (_Float16)v1.y, (_Float16)v1.z, (_Float16)v1.w};
  _Float16* dst = X + (size_t)row * E_ + e8 * 8;
  *(half4*)dst = o0;
  *(half4*)(dst + 4) = o1;
}

__global__ __launch_bounds__(512, 1) void lstm_kernel(
    const _Float16* __restrict__ X,
    const float* __restrict__ Wx, const float* __restrict__ Wh,
    const float* __restrict__ bias,
    _Float16* __restrict__ H0, _Float16* __restrict__ H1,
    int* flags) {
  // LDS: Wl [64 cols][KP_] fp16 (98,816 B) | Hs [32 rows][HROW_] fp16
  // (33,280 B) | Rs reduce scratch float[8][256] (8,192 B) = 140,288 B.
  __shared__ __align__(16) char smem[140288];
  _Float16* Wl = (_Float16*)smem;
  _Float16* Hs = (_Float16*)(smem + 98816);
  float* Rs = (float*)(smem + 132096);

  const int g = blockIdx.x;
  const int q = g >> 5;   // batch quarter: rows q*32 .. q*32+31
  const int s = g & 31;   // unit slice: units s*16 .. s*16+15
  const int tid = threadIdx.x;
  const int lane = tid & 63;
  const int wave = tid >> 6;      // 8 waves
  const int p16 = lane & 15;
  const int quad = lane >> 4;
  const int sg = wave & 1;        // unit subgroup (8 units)
  const int mt = (wave >> 1) & 1; // M-tile (16 batch rows)
  const int kh = wave >> 2;       // K-half: 0 = x + h[256:512), 1 = h[0:256)

  // ---- one-time: stage weight slice [768 x 64] into LDS ----
  // col c: c>>5 = sg; cc=c&31: cc<16 -> [i u0..7 | f u0..7], cc>=16 -> [g|o].
  for (int idx = tid; idx < 64 * 768; idx += 512) {
    int c = idx & 63, k = idx >> 6;
    int cc = c & 31;
    int gi = ((cc >> 3) & 1) + ((cc >> 4) << 1);       // 0=i,1=f,2=g,3=o
    int C = gi * 512 + s * 16 + (c >> 5) * 8 + (cc & 7);
    float w = (k < E_) ? Wx[(size_t)k * 2048 + C] : Wh[(size_t)(k - E_) * 2048 + C];
    Wl[c * KP_ + k] = (_Float16)w;
  }
  __syncthreads();

  const bool lo = (p16 < 8);
  const int uo = p16 & 7;
  const int gu = s * 16 + sg * 8 + uo;               // global unit id
  const float bias0 = bias[(lo ? 0 : 512) + gu];     // i or f
  const float bias1 = bias[(lo ? 1024 : 1536) + gu]; // g or o

  float cst[4] = {0.f, 0.f, 0.f, 0.f};  // c-state (kh0 lo lanes only)

  const int brow = q * 32 + mt * 16 + p16;  // global batch row (A-frag)
  const int ko = quad * 4;

  const _Float16* bp0 = &Wl[(sg * 32 + p16) * KP_ + ko];       // [i|f] col
  const _Float16* bp1 = &Wl[(sg * 32 + 16 + p16) * KP_ + ko];  // [g|o] col

  for (int t = 0; t < T_; ++t) {
    floatx4 acc0 = {0.f, 0.f, 0.f, 0.f};
    floatx4 acc1 = {0.f, 0.f, 0.f, 0.f};

    // ---- x-part (kh0 waves): no h_t dependency -> overlaps producer wait ----
    if (kh == 0) {
      const _Float16* xr = X + ((size_t)t * B_ + brow) * E_ + ko;
#pragma unroll
      for (int kk = 0; kk < 16; ++kk) {
        half4 a = *(const half4*)(xr + kk * 16);
        half4 b0 = *(const half4*)(bp0 + kk * 16);
        half4 b1 = *(const half4*)(bp1 + kk * 16);
        acc0 = __builtin_amdgcn_mfma_f32_16x16x16f16(a, b0, acc0, 0, 0, 0);
        acc1 = __builtin_amdgcn_mfma_f32_16x16x16f16(a, b1, acc1, 0, 0, 0);
      }
    }

    // ---- wait: our quarter's 32 producers published h_t ----
    if (wave == 0) {
      const int fi = (q * 32 + (lane & 31)) * 16;
      for (;;) {
        int v = __hip_atomic_load(&flags[fi], __ATOMIC_RELAXED,
                                  __HIP_MEMORY_SCOPE_AGENT);
        if (__all(v >= t)) break;
        __builtin_amdgcn_s_sleep(1);
      }
    }
    __syncthreads();  // B1

    const _Float16* __restrict__ Hin = (t & 1) ? H1 : H0;
    _Float16* __restrict__ Hout = (t & 1) ? H0 : H1;

    // ---- stage H quarter-slab (32 rows x 1KB): 8 coalesced 512B chunks/wave ----
    u64t hv[8];
#pragma unroll
    for (int j = 0; j < 8; ++j) {
      int ci = wave * 8 + j, r = ci >> 1, hf = ci & 1;
      const u64t* src =
          (const u64t*)(Hin + (size_t)(q * 32 + r) * U_ + hf * 256) + lane;
      hv[j] = __hip_atomic_load(src, __ATOMIC_RELAXED, __HIP_MEMORY_SCOPE_AGENT);
    }
#pragma unroll
    for (int j = 0; j < 8; ++j) {
      int ci = wave * 8 + j, r = ci >> 1, hf = ci & 1;
      *(u64t*)(Hs + r * HROW_ + hf * 256 + lane * 4) = hv[j];
    }
    __syncthreads();  // B2

    // ---- h-part from slab: kh0 -> h-cols [256,512), kh1 -> [0,256) ----
    const _Float16* ar = Hs + (mt * 16 + p16) * HROW_ + ko;
    const int hbase = kh ? 0 : 16;
#pragma unroll
    for (int kk = 0; kk < 16; ++kk) {
      int hk = hbase + kk;
      half4 a = *(const half4*)(ar + hk * 16);
      half4 b0 = *(const half4*)(bp0 + 256 + hk * 16);
      half4 b1 = *(const half4*)(bp1 + 256 + hk * 16);
      acc0 = __builtin_amdgcn_mfma_f32_16x16x16f16(a, b0, acc0, 0, 0, 0);
      acc1 = __builtin_amdgcn_mfma_f32_16x16x16f16(a, b1, acc1, 0, 0, 0);
    }

    // ---- partial-sum reduce: kh1 -> LDS (conflict-free b32 layout) ----
    if (kh == 1) {
      int base = (wave - 4) * 64 + lane;
#pragma unroll
      for (int r = 0; r < 4; ++r) {
        Rs[r * 256 + base] = acc0[r];
        Rs[(4 + r) * 256 + base] = acc1[r];
      }
    }
    __syncthreads();  // B3

    // ---- epilogue (kh0 waves): gates, c/h update, publish h ----
    if (kh == 0) {
      int base = wave * 64 + lane;
#pragma unroll
      for (int r = 0; r < 4; ++r) {
        float z0 = acc0[r] + Rs[r * 256 + base] + bias0;       // i (lo)/ f (hi)
        float z1 = acc1[r] + Rs[(4 + r) * 256 + base] + bias1; // g (lo)/ o (hi)
        float s0 = sigmf(z0);
        float s1 = lo ? tanh_f(z1) : sigmf(z1);
        float prod = s0 * s1;                          // i*g on lo lanes
        float fg = __shfl_xor(lo ? prod : s0, 8, 64);  // lo receives f
        float og = __shfl_xor(s1, 8, 64);              // lo receives o
        if (lo) {
          float cn = fg * cst[r] + prod;
          cst[r] = cn;
          float h = og * tanh_f(cn);
          int row = q * 32 + mt * 16 + quad * 4 + r;
          _Float16 hf16 = (_Float16)h;
          unsigned short hb = __builtin_bit_cast(unsigned short, hf16);
          __hip_atomic_store((unsigned short*)&Hout[(size_t)row * U_ + gu], hb,
                             __ATOMIC_RELAXED, __HIP_MEMORY_SCOPE_AGENT);
        }
      }
    }

    // ---- publish: B4 drains vmcnt(0) (stores at LLC) before flag ----
    __syncthreads();  // B4
    if (tid == 0)
      __hip_atomic_store(&flags[g * 16], t + 1, __ATOMIC_RELAXED,
                         __HIP_MEMORY_SCOPE_AGENT);
  }
}

// MLP head: one block per batch row. h(512)->relu 128->relu 64->sigmoid 1.
__global__ void head_kernel(const _Float16* __restrict__ H0,
                            const float* __restrict__ W1, const float* __restrict__ b1,
                            const float* __restrict__ W2, const float* __restrict__ b2,
                            const float* __restrict__ W3, const float* __restrict__ b3,
                            float* __restrict__ out) {
  __shared__ float hs[512];
  __shared__ float h1[128];
  __shared__ float h2[64];
  int row = blockIdx.x;
  int tid = threadIdx.x;  // 128 threads
  for (int k = tid; k < 512; k += 128) hs[k] = (float)H0[(size_t)row * U_ + k];
  __syncthreads();
  float a = b1[tid];
  for (int k = 0; k < 512; ++k) a += hs[k] * W1[k * 128 + tid];
  h1[tid] = fmaxf(a, 0.0f);
  __syncthreads();
  if (tid < 64) {
    float a2 = b2[tid];
    for (int k = 0; k < 128; ++k) a2 += h1[k] * W2[k * 64 + tid];
    h2[tid] = fmaxf(a2, 0.0f);
  }
  __syncthreads();
  if (tid == 0) {
    float a3 = b3[0];
    for (int k = 0; k < 64; ++k) a3 += h2[k] * W3[k];
    out[row] = 1.0f / (1.0f + __expf(-a3));
  }
}

extern "C" void kernel_launch(void* const* d_in, const int* in_sizes, int n_in,
                              void* d_out, int out_size, void* d_ws, size_t ws_size,
                              hipStream_t stream) {
  const int* sent = (const int*)d_in[0];
  const float* emb = (const float*)d_in[1];
  const float* Wx = (const float*)d_in[2];
  const float* Wh = (const float*)d_in[3];
  const float* b = (const float*)d_in[4];
  const float* W1 = (const float*)d_in[5];
  const float* b1 = (const float*)d_in[6];
  const float* W2 = (const float*)d_in[7];
  const float* b2 = (const float*)d_in[8];
  const float* W3 = (const float*)d_in[9];
  const float* b3 = (const float*)d_in[10];
  float* out = (float*)d_out;

  char* ws = (char*)d_ws;
  _Float16* X = (_Float16*)(ws);
  _Float16* H0 = (_Float16*)(ws + (size_t)33554432);
  _Float16* H1 = (_Float16*)(ws + (size_t)33554432 + 131072);
  int* flags = (int*)(ws + (size_t)33554432 + 262144);

  init_ws_kernel<<<64, 256, 0, stream>>>((unsigned int*)H0, (unsigned int*)flags);
  prep_x_kernel<<<8192, 256, 0, stream>>>(sent, emb, X);
  lstm_kernel<<<NWG_, 512, 0, stream>>>(X, Wx, Wh, b, H0, H1, flags);
  head_kernel<<<128, 128, 0, stream>>>(H0, W1, b1, W2, b2, W3, b3, out);
}

// Round 4
// 2698.574 us; speedup vs baseline: 4.2408x; 1.0545x over previous
//
#include <hip/hip_runtime.h>
#include <hip/hip_bf16.h>
#include <hip/hip_fp16.h>

// LSTM_RNN: B=128, T=512, E=256, U=512. R4: tag-in-data handshake.
//   - 128 wgs = 4 batch-quarters x 32 unit-slices (16 units / 64 gate cols).
//   - H buffers are u32[128][512]: (step_tag << 16) | fp16 bits. Producers
//     store tagged values (relaxed agent atomics, straight to LLC) and move
//     on -- NO flag, NO drain barrier. Consumers retry-load their staging
//     chunks until tags == t (masked reload of stale chunks only). One LLC
//     round-trip per step instead of flag-RT + data-RT; 2 barriers/step not 4.
//   - Safety: a wg enters step t only after ALL producers of its quarter
//     published tag t (per-value gating = same happens-before as flags).
//     Stale slot = tag t-2 (double buffer) or 0xAAAA poison -> spin, never
//     false-positive. 16-bit tag, T=512 fits.
//   - kh1 waves (4..7) run the x-GEMM (no h dependency) -- overlaps kh0's
//     epilogue of the previous step. kh0 waves do gates/c/h + tagged stores.
//   - LDS 140,288 B static; 512 thr (8 waves); weights [768x64] fp16 resident.
// ws layout (~34.1 MiB):
//   X   fp16 [T][B][E]   @ 0          (33,554,432 B)
//   H0  u32  [B][U]      @ 33,554,432 (262,144 B)
//   H1  u32  [B][U]      @ 33,816,576 (262,144 B)

#define B_ 128
#define T_ 512
#define E_ 256
#define U_ 512
#define NWG_ 128
#define KP_ 772     // weight row stride (halves)
#define HROW_ 520   // H-slab row stride (halves)

typedef __attribute__((ext_vector_type(4))) _Float16 half4;
typedef __attribute__((ext_vector_type(4))) float floatx4;
typedef unsigned long long u64t;
typedef unsigned int u32t;

__device__ __forceinline__ float sigmf(float x) { return 1.0f / (1.0f + __expf(-x)); }
__device__ __forceinline__ float tanh_f(float x) { return 2.0f / (1.0f + __expf(-2.0f * x)) - 1.0f; }

__global__ void init_ws_kernel(u32t* __restrict__ h0w) {
  int gid = blockIdx.x * blockDim.x + threadIdx.x;
  int n = blockDim.x * gridDim.x;
  for (int i = gid; i < B_ * U_; i += n) h0w[i] = 0u;  // h_0 = 0, tag 0
}

// X[t][b][e] = (fp16) emb[sentence[b][t]][e]; one thread = 8 elements.
__global__ void prep_x_kernel(const int* __restrict__ sent,
                              const float* __restrict__ emb,
                              _Float16* __restrict__ X) {
  int gid = blockIdx.x * blockDim.x + threadIdx.x;  // 2,097,152 total
  int e8 = gid & 31;
  int row = gid >> 5;         // row = t*128 + b
  int b = row & 127;
  int t = row >> 7;
  int word = sent[b * T_ + t];
  const float* src = emb + (size_t)word * E_ + e8 * 8;
  float4 v0 = *(const float4*)(src);
  float4 v1 = *(const float4*)(src + 4);
  half4 o0 = {(_Float16)v0.x, (_Float16)v0.y, (_Float16)v0.z, (_Float16)v0.w};
  half4 o1 = {(_Float16)v1.x, (_Float16)v1.y, (_Float16)v1.z, (_Float16)v1.w};
  _Float16* dst = X + (size_t)row * E_ + e8 * 8;
  *(half4*)dst = o0;
  *(half4*)(dst + 4) = o1;
}

__global__ __launch_bounds__(512, 1) void lstm_kernel(
    const _Float16* __restrict__ X,
    const float* __restrict__ Wx, const float* __restrict__ Wh,
    const float* __restrict__ bias,
    u32t* __restrict__ H0, u32t* __restrict__ H1) {
  // LDS: Wl [64][KP_] fp16 (98,816 B) | Hs [32][HROW_] fp16 (33,280 B) |
  //      Rs float[8][256] (8,192 B) = 140,288 B.
  __shared__ __align__(16) char smem[140288];
  _Float16* Wl = (_Float16*)smem;
  _Float16* Hs = (_Float16*)(smem + 98816);
  float* Rs = (float*)(smem + 132096);

  const int g = blockIdx.x;
  const int q = g >> 5;   // batch quarter: rows q*32 .. q*32+31
  const int s = g & 31;   // unit slice: units s*16 .. s*16+15
  const int tid = threadIdx.x;
  const int lane = tid & 63;
  const int wave = tid >> 6;      // 8 waves
  const int p16 = lane & 15;
  const int quad = lane >> 4;
  const int sg = wave & 1;        // unit subgroup (8 units)
  const int mt = (wave >> 1) & 1; // M-tile (16 batch rows)
  const int kh = wave >> 2;       // 0: h[256,512)+epilogue, 1: x + h[0,256)

  // ---- one-time: stage weight slice [768 x 64] into LDS ----
  for (int idx = tid; idx < 64 * 768; idx += 512) {
    int c = idx & 63, k = idx >> 6;
    int cc = c & 31;
    int gi = ((cc >> 3) & 1) + ((cc >> 4) << 1);       // 0=i,1=f,2=g,3=o
    int C = gi * 512 + s * 16 + (c >> 5) * 8 + (cc & 7);
    float w = (k < E_) ? Wx[(size_t)k * 2048 + C] : Wh[(size_t)(k - E_) * 2048 + C];
    Wl[c * KP_ + k] = (_Float16)w;
  }
  __syncthreads();

  const bool lo = (p16 < 8);
  const int uo = p16 & 7;
  const int gu = s * 16 + sg * 8 + uo;               // global unit id
  const float bias0 = bias[(lo ? 0 : 512) + gu];     // i or f
  const float bias1 = bias[(lo ? 1024 : 1536) + gu]; // g or o

  float cst[4] = {0.f, 0.f, 0.f, 0.f};  // c-state (kh0 lo lanes)

  const int brow = q * 32 + mt * 16 + p16;  // A-frag batch row
  const int ko = quad * 4;

  const _Float16* bp0 = &Wl[(sg * 32 + p16) * KP_ + ko];       // [i|f] col
  const _Float16* bp1 = &Wl[(sg * 32 + 16 + p16) * KP_ + ko];  // [g|o] col

  for (int t = 0; t < T_; ++t) {
    const u32t* __restrict__ Hin = (t & 1) ? H1 : H0;
    u32t* __restrict__ Hout = (t & 1) ? H0 : H1;

    floatx4 acc0 = {0.f, 0.f, 0.f, 0.f};
    floatx4 acc1 = {0.f, 0.f, 0.f, 0.f};

    // ---- x-part on kh1 (overlaps kh0's previous-step epilogue) ----
    if (kh == 1) {
      const _Float16* xr = X + ((size_t)t * B_ + brow) * E_ + ko;
#pragma unroll
      for (int kk = 0; kk < 16; ++kk) {
        half4 a = *(const half4*)(xr + kk * 16);
        half4 b0 = *(const half4*)(bp0 + kk * 16);
        half4 b1 = *(const half4*)(bp1 + kk * 16);
        acc0 = __builtin_amdgcn_mfma_f32_16x16x16f16(a, b0, acc0, 0, 0, 0);
        acc1 = __builtin_amdgcn_mfma_f32_16x16x16f16(a, b1, acc1, 0, 0, 0);
      }
    }

    // ---- consume h_t: retry-load own chunks until tags == t ----
    // chunk ci = wave*16+j: row = ci>>2, seg = ci&3 (128 u32 per seg);
    // lane covers u32 pair -> units seg*128 + lane*2, +1.
    u64t hv[16];
    u32t done = 0;
    const u32t tgt = (u32t)t;
    for (;;) {
#pragma unroll
      for (int j = 0; j < 16; ++j) {
        if (!((done >> j) & 1)) {
          int ci = wave * 16 + j;
          int r = ci >> 2, seg = ci & 3;
          const u64t* src =
              (const u64t*)(Hin + (size_t)(q * 32 + r) * U_ + seg * 128) + lane;
          hv[j] = __hip_atomic_load(src, __ATOMIC_RELAXED,
                                    __HIP_MEMORY_SCOPE_AGENT);
        }
      }
      u32t nd = done;
#pragma unroll
      for (int j = 0; j < 16; ++j) {
        if (!((nd >> j) & 1)) {
          u32t lo32 = (u32t)hv[j];
          u32t hi32 = (u32t)(hv[j] >> 32);
          if (((lo32 >> 16) == tgt) & ((hi32 >> 16) == tgt)) nd |= (1u << j);
        }
      }
      done = nd;
      if (__all(done == 0xffffu)) break;
      __builtin_amdgcn_s_sleep(1);
    }
    // strip tags -> fp16 slab in LDS
#pragma unroll
    for (int j = 0; j < 16; ++j) {
      int ci = wave * 16 + j;
      int r = ci >> 2, seg = ci & 3;
      u32t packed = ((u32t)hv[j] & 0xffffu) |
                    ((u32t)(hv[j] >> 16) & 0xffff0000u);
      *(u32t*)(Hs + r * HROW_ + seg * 128 + lane * 2) = packed;
    }
    __syncthreads();  // B2: slab ready

    // ---- h-part from slab: kh0 -> cols [256,512), kh1 -> [0,256) ----
    const _Float16* ar = Hs + (mt * 16 + p16) * HROW_ + ko;
    const int hbase = kh ? 0 : 16;
#pragma unroll
    for (int kk = 0; kk < 16; ++kk) {
      int hk = hbase + kk;
      half4 a = *(const half4*)(ar + hk * 16);
      half4 b0 = *(const half4*)(bp0 + 256 + hk * 16);
      half4 b1 = *(const half4*)(bp1 + 256 + hk * 16);
      acc0 = __builtin_amdgcn_mfma_f32_16x16x16f16(a, b0, acc0, 0, 0, 0);
      acc1 = __builtin_amdgcn_mfma_f32_16x16x16f16(a, b1, acc1, 0, 0, 0);
    }

    // ---- kh1 partials -> LDS ----
    if (kh == 1) {
      int base = (wave - 4) * 64 + lane;
#pragma unroll
      for (int r = 0; r < 4; ++r) {
        Rs[r * 256 + base] = acc0[r];
        Rs[(4 + r) * 256 + base] = acc1[r];
      }
    }
    __syncthreads();  // B3: partials ready; also fences Hs reuse next step

    // ---- epilogue (kh0): gates, c/h update, tagged publish ----
    if (kh == 0) {
      int base = wave * 64 + lane;
#pragma unroll
      for (int r = 0; r < 4; ++r) {
        float z0 = acc0[r] + Rs[r * 256 + base] + bias0;       // i (lo)/ f (hi)
        float z1 = acc1[r] + Rs[(4 + r) * 256 + base] + bias1; // g (lo)/ o (hi)
        float s0 = sigmf(z0);
        float s1 = lo ? tanh_f(z1) : sigmf(z1);
        float prod = s0 * s1;                          // i*g on lo lanes
        float fg = __shfl_xor(lo ? prod : s0, 8, 64);  // lo receives f
        float og = __shfl_xor(s1, 8, 64);              // lo receives o
        if (lo) {
          float cn = fg * cst[r] + prod;
          cst[r] = cn;
          float h = og * tanh_f(cn);
          int row = q * 32 + mt * 16 + quad * 4 + r;
          _Float16 hf16 = (_Float16)h;
          u32t hb = ((u32t)(t + 1) << 16) |
                    (u32t)__builtin_bit_cast(unsigned short, hf16);
          __hip_atomic_store(&Hout[(size_t)row * U_ + gu], hb,
                             __ATOMIC_RELAXED, __HIP_MEMORY_SCOPE_AGENT);
        }
      }
    }
    // no end barrier: consumers gate on tags, not on flags.
  }
}

// MLP head: one block per batch row. h(512)->relu 128->relu 64->sigmoid 1.
__global__ void head_kernel(const u32t* __restrict__ H0,
                            const float* __restrict__ W1, const float* __restrict__ b1,
                            const float* __restrict__ W2, const float* __restrict__ b2,
                            const float* __restrict__ W3, const float* __restrict__ b3,
                            float* __restrict__ out) {
  __shared__ float hs[512];
  __shared__ float h1[128];
  __shared__ float h2[64];
  int row = blockIdx.x;
  int tid = threadIdx.x;  // 128 threads
  for (int k = tid; k < 512; k += 128) {
    unsigned short hb = (unsigned short)(H0[(size_t)row * U_ + k] & 0xffffu);
    hs[k] = (float)__builtin_bit_cast(_Float16, hb);
  }
  __syncthreads();
  float a = b1[tid];
  for (int k = 0; k < 512; ++k) a += hs[k] * W1[k * 128 + tid];
  h1[tid] = fmaxf(a, 0.0f);
  __syncthreads();
  if (tid < 64) {
    float a2 = b2[tid];
    for (int k = 0; k < 128; ++k) a2 += h1[k] * W2[k * 64 + tid];
    h2[tid] = fmaxf(a2, 0.0f);
  }
  __syncthreads();
  if (tid == 0) {
    float a3 = b3[0];
    for (int k = 0; k < 64; ++k) a3 += h2[k] * W3[k];
    out[row] = 1.0f / (1.0f + __expf(-a3));
  }
}

extern "C" void kernel_launch(void* const* d_in, const int* in_sizes, int n_in,
                              void* d_out, int out_size, void* d_ws, size_t ws_size,
                              hipStream_t stream) {
  const int* sent = (const int*)d_in[0];
  const float* emb = (const float*)d_in[1];
  const float* Wx = (const float*)d_in[2];
  const float* Wh = (const float*)d_in[3];
  const float* b = (const float*)d_in[4];
  const float* W1 = (const float*)d_in[5];
  const float* b1 = (const float*)d_in[6];
  const float* W2 = (const float*)d_in[7];
  const float* b2 = (const float*)d_in[8];
  const float* W3 = (const float*)d_in[9];
  const float* b3 = (const float*)d_in[10];
  float* out = (float*)d_out;

  char* ws = (char*)d_ws;
  _Float16* X = (_Float16*)(ws);
  u32t* H0 = (u32t*)(ws + (size_t)33554432);
  u32t* H1 = (u32t*)(ws + (size_t)33554432 + 262144);

  init_ws_kernel<<<64, 256, 0, stream>>>(H0);
  prep_x_kernel<<<8192, 256, 0, stream>>>(sent, emb, X);
  lstm_kernel<<<NWG_, 512, 0, stream>>>(X, Wx, Wh, b, H0, H1);
  head_kernel<<<128, 128, 0, stream>>>(H0, W1, b1, W2, b2, W3, b3, out);
}